// Round 10
// baseline (199.423 us; speedup 1.0000x reference)
//
#include <hip/hip_runtime.h>
#include <hip/hip_bf16.h>
#include <math.h>

#define N_NODES  30000
#define N_EDGESR 480000
#define E_TOT    (N_EDGESR + N_NODES)
#define N_GRAPHS 64
#define IN_DIM   128
#define HID      64
#define NEG_SLOPE 0.2f

typedef __attribute__((ext_vector_type(8))) short bf16x8;
typedef __attribute__((ext_vector_type(8))) unsigned short u16x8;
typedef __attribute__((ext_vector_type(4))) float f32x4;

__device__ __forceinline__ float lrelu(float v) { return v > 0.f ? v : NEG_SLOPE * v; }
__device__ __forceinline__ float bf2f(unsigned short u) { return __uint_as_float((unsigned)u << 16); }
__device__ __forceinline__ unsigned short f2bf(float f) {
    return __bfloat16_as_ushort(__float2bfloat16(f));
}

// ---- fused prep ∥ hist: x->bf16, W transposes, zero pool, edge histogram ----
// counts must be zeroed (hipMemsetAsync) BEFORE this kernel.
__global__ __launch_bounds__(256) void prep_hist_kernel(const float* __restrict__ x,
                                                        const float* __restrict__ W1,
                                                        const float* __restrict__ W2,
                                                        const int* __restrict__ ei,
                                                        unsigned short* __restrict__ xb,
                                                        unsigned short* __restrict__ w1t,
                                                        unsigned short* __restrict__ w2t,
                                                        int* __restrict__ counts,
                                                        unsigned* __restrict__ g) {
    int t = blockIdx.x * 256 + threadIdx.x;
    if (t < 480000) {                               // x -> bf16, 8 elems/thread
        int i = t * 8;
        float4 v0 = *reinterpret_cast<const float4*>(x + i);
        float4 v1 = *reinterpret_cast<const float4*>(x + i + 4);
        u16x8 o;
        o[0] = f2bf(v0.x); o[1] = f2bf(v0.y); o[2] = f2bf(v0.z); o[3] = f2bf(v0.w);
        o[4] = f2bf(v1.x); o[5] = f2bf(v1.y); o[6] = f2bf(v1.z); o[7] = f2bf(v1.w);
        *reinterpret_cast<u16x8*>(xb + i) = o;
    } else if (t < 484096) {
        g[t - 480000] = 0u;
    } else if (t < 516864) {                        // W1 [128][256] -> w1t [256][128]
        int id = t - 484096;
        int k = id >> 8, n = id & 255;
        w1t[n * 128 + k] = f2bf(W1[id]);
    } else if (t < 533248) {                        // W2 [256][64] -> w2t [64][256]
        int id = t - 516864;
        int k = id >> 6, n = id & 63;
        w2t[n * 256 + k] = f2bf(W2[id]);
    } else if (t < 533248 + E_TOT) {                // edge histogram
        int e = t - 533248;
        int d = (e < N_EDGESR) ? ei[N_EDGESR + e] : (e - N_EDGESR);
        atomicAdd(&counts[d], 1);
    }
}

__global__ __launch_bounds__(1024) void scan_counts(const int* __restrict__ counts,
                                                    int* __restrict__ rowstart,
                                                    int* __restrict__ cursor) {
    __shared__ int bufA[1024];
    __shared__ int bufB[1024];
    const int t = threadIdx.x;
    const int CH = 30;
    int local[CH];
    int base = t * CH;
    int s = 0;
    #pragma unroll
    for (int i = 0; i < CH; ++i) {
        int idx = base + i;
        int c = (idx < N_NODES) ? counts[idx] : 0;
        local[i] = c; s += c;
    }
    bufA[t] = s;
    __syncthreads();
    int* a = bufA; int* b = bufB;
    for (int off = 1; off < 1024; off <<= 1) {
        int v = a[t] + ((t >= off) ? a[t - off] : 0);
        b[t] = v;
        __syncthreads();
        int* tmp = a; a = b; b = tmp;
    }
    int run = (t == 0) ? 0 : a[t - 1];
    #pragma unroll
    for (int i = 0; i < CH; ++i) {
        int idx = base + i;
        if (idx < N_NODES) { rowstart[idx] = run; cursor[idx] = run; run += local[i]; }
    }
    if (t == 0) rowstart[N_NODES] = E_TOT;
}

// ---- fused: edge scatter ∥ MFMA GEMM1 (both ready after scan; gemm1 needs only prep) ----
#define SCAT_B 1993
__global__ __launch_bounds__(256) void scatter_gemm1(const int* __restrict__ ei,
                                                     int* __restrict__ cursor,
                                                     int* __restrict__ srcidx,
                                                     const unsigned short* __restrict__ xb,
                                                     const unsigned short* __restrict__ w1t,
                                                     unsigned short* __restrict__ h1,
                                                     const float* __restrict__ att_src,
                                                     const float* __restrict__ att_dst,
                                                     float* __restrict__ a_src,
                                                     float* __restrict__ a_dst) {
    __shared__ __align__(16) unsigned short As[64 * 128];  // 16 KB (gemm branch only)
    const int b = blockIdx.x;
    const int tid = threadIdx.x;
    if (b < SCAT_B) {                                  // edge scatter
        int e = b * 256 + tid;
        if (e >= E_TOT) return;
        int s, d;
        if (e < N_EDGESR) { s = ei[e]; d = ei[N_EDGESR + e]; }
        else              { s = d = e - N_EDGESR; }
        int pos = atomicAdd(&cursor[d], 1);
        srcidx[pos] = s;
        return;
    }
    // ---- MFMA GEMM1: h1 = xb @ W1, fused attn dots ----
    const int w = tid >> 6;
    const int l = tid & 63;
    const int rowbase = (b - SCAT_B) * 64;
    char* Ab = (char*)As;

    #pragma unroll
    for (int i = 0; i < 4; ++i) {
        int flat = i * 256 + tid;            // 16B-chunk id 0..1023
        int r = flat >> 4;                   // row 0..63
        int cb = (flat & 15) * 16;           // byte col
        int gr = rowbase + r; if (gr >= N_NODES) gr = N_NODES - 1;
        int4 v = *reinterpret_cast<const int4*>(xb + (size_t)gr * 128 + (cb >> 1));
        *reinterpret_cast<int4*>(Ab + r * 256 + (cb ^ ((r & 7) << 4))) = v;
    }
    __syncthreads();

    const int lm = l & 15, lh = l >> 4;
    f32x4 acc[4][4];
    #pragma unroll
    for (int rt = 0; rt < 4; ++rt)
        #pragma unroll
        for (int ct = 0; ct < 4; ++ct)
            acc[rt][ct] = (f32x4){0.f, 0.f, 0.f, 0.f};

    #pragma unroll
    for (int s = 0; s < 4; ++s) {
        bf16x8 bfr[4], afr[4];
        #pragma unroll
        for (int ct = 0; ct < 4; ++ct) {
            int n = w * 64 + ct * 16 + lm;
            bfr[ct] = *reinterpret_cast<const bf16x8*>(w1t + n * 128 + s * 32 + lh * 8);
        }
        #pragma unroll
        for (int rt = 0; rt < 4; ++rt) {
            int row = rt * 16 + lm;
            int cb = s * 64 + lh * 16;
            afr[rt] = *reinterpret_cast<const bf16x8*>(Ab + row * 256 + (cb ^ ((row & 7) << 4)));
        }
        #pragma unroll
        for (int rt = 0; rt < 4; ++rt)
            #pragma unroll
            for (int ct = 0; ct < 4; ++ct)
                acc[rt][ct] = __builtin_amdgcn_mfma_f32_16x16x32_bf16(bfr[ct], afr[rt], acc[rt][ct], 0, 0, 0);
    }

    // epilogue: bf16 C write (8B packed) + fused attention dots for head w
    #pragma unroll
    for (int rt = 0; rt < 4; ++rt) {
        int row = rowbase + rt * 16 + lm;
        float ps = 0.f, pd = 0.f;
        #pragma unroll
        for (int ct = 0; ct < 4; ++ct) {
            int col = w * 64 + ct * 16 + lh * 4;
            if (row < N_NODES) {
                ushort4 o;
                o.x = f2bf(acc[rt][ct][0]); o.y = f2bf(acc[rt][ct][1]);
                o.z = f2bf(acc[rt][ct][2]); o.w = f2bf(acc[rt][ct][3]);
                *reinterpret_cast<ushort4*>(h1 + (size_t)row * 256 + col) = o;
            }
            #pragma unroll
            for (int q = 0; q < 4; ++q) {
                ps += acc[rt][ct][q] * att_src[col + q];
                pd += acc[rt][ct][q] * att_dst[col + q];
            }
        }
        ps += __shfl_xor(ps, 16); ps += __shfl_xor(ps, 32);
        pd += __shfl_xor(pd, 16); pd += __shfl_xor(pd, 32);
        if (lh == 0 && row < N_NODES) {
            a_src[row * 4 + w] = ps;
            a_dst[row * 4 + w] = pd;
        }
    }
}

// ---------------- GAT layer-1 aggregation — 128-thread blocks (2 waves) to cut imbalance ----------------
__global__ __launch_bounds__(128) void gat_agg1(const unsigned short* __restrict__ h1,
                                                const float* __restrict__ a_src,
                                                const float* __restrict__ a_dst,
                                                const int* __restrict__ rowstart,
                                                const int* __restrict__ srcidx,
                                                const float* __restrict__ b1,
                                                unsigned short* __restrict__ out1) {
    int n = blockIdx.x * 2 + (threadIdx.x >> 6);
    int lane = threadIdx.x & 63;
    if (n >= N_NODES) return;
    int beg = rowstart[n], end = rowstart[n + 1];
    const int h    = lane & 3;
    const int slot = lane >> 2;
    const int half = lane >> 5;
    const int cl   = lane & 31;
    const int myhead = cl >> 3;
    float ad_h = a_dst[n * 4 + h];

    float acc[8] = {};
    float den_part = 0.f;
    int cb = beg;
    for (; cb + 16 <= end; cb += 16) {
        int s = srcidx[cb + slot];
        float w = __expf(lrelu(a_src[s * 4 + h] + ad_h));   // bounded logits: no max needed
        den_part += w;
        #pragma unroll
        for (int j = 0; j < 16; j += 2) {
            int e = j + half;
            float wj = __shfl(w, e * 4 + myhead);
            int   sj = __shfl(s, e * 4);
            u16x8 hv = *reinterpret_cast<const u16x8*>(h1 + (size_t)sj * 256 + cl * 8);
            #pragma unroll
            for (int q = 0; q < 8; ++q) acc[q] += wj * bf2f((unsigned short)hv[q]);
        }
    }
    if (cb < end) {
        int cnt = end - cb;                      // 1..15
        float w = 0.f; int s = 0;
        if (slot < cnt) {
            s = srcidx[cb + slot];
            w = __expf(lrelu(a_src[s * 4 + h] + ad_h));
            den_part += w;
        }
        for (int j = 0; j < cnt; j += 2) {
            int e = j + half;
            float wj = __shfl(w, e * 4 + myhead);
            int   sj = __shfl(s, e * 4);
            if (e < cnt) {
                u16x8 hv = *reinterpret_cast<const u16x8*>(h1 + (size_t)sj * 256 + cl * 8);
                #pragma unroll
                for (int q = 0; q < 8; ++q) acc[q] += wj * bf2f((unsigned short)hv[q]);
            }
        }
    }
    #pragma unroll
    for (int q = 0; q < 8; ++q) acc[q] += __shfl_xor(acc[q], 32);
    #pragma unroll
    for (int off = 4; off < 64; off <<= 1) den_part += __shfl_xor(den_part, off);
    float inv = 1.f / __shfl(den_part, myhead);
    if (half == 0) {
        float4 bv0 = *reinterpret_cast<const float4*>(b1 + cl * 8);
        float4 bv1 = *reinterpret_cast<const float4*>(b1 + cl * 8 + 4);
        u16x8 o;
        o[0] = f2bf(fmaxf(acc[0] * inv + bv0.x, 0.f));
        o[1] = f2bf(fmaxf(acc[1] * inv + bv0.y, 0.f));
        o[2] = f2bf(fmaxf(acc[2] * inv + bv0.z, 0.f));
        o[3] = f2bf(fmaxf(acc[3] * inv + bv0.w, 0.f));
        o[4] = f2bf(fmaxf(acc[4] * inv + bv1.x, 0.f));
        o[5] = f2bf(fmaxf(acc[5] * inv + bv1.y, 0.f));
        o[6] = f2bf(fmaxf(acc[6] * inv + bv1.z, 0.f));
        o[7] = f2bf(fmaxf(acc[7] * inv + bv1.w, 0.f));
        __builtin_nontemporal_store(o, reinterpret_cast<u16x8*>(out1 + (size_t)n * 256 + cl * 8));
    }
}

// ---- MFMA GEMM2: h2[30000,64] = out1[30000,256] @ W2 (w2t [64][256] bf16) + fused attn dots ----
__global__ __launch_bounds__(256) void mfma_gemm2(const unsigned short* __restrict__ a1b,
                                                  const unsigned short* __restrict__ w2t,
                                                  unsigned short* __restrict__ h2,
                                                  const float* __restrict__ att_src,
                                                  const float* __restrict__ att_dst,
                                                  float* __restrict__ a_src,
                                                  float* __restrict__ a_dst) {
    __shared__ __align__(16) unsigned short As[64 * 256];  // 32 KB, swizzled
    __shared__ float ps_s[4][64], pd_s[4][64];
    const int tid = threadIdx.x;
    const int w = tid >> 6, l = tid & 63;
    const int rowbase = blockIdx.x * 64;
    char* Ab = (char*)As;

    #pragma unroll
    for (int i = 0; i < 8; ++i) {
        int flat = i * 256 + tid;
        int r = flat >> 5;
        int cb = (flat & 31) * 16;
        int gr = rowbase + r; if (gr >= N_NODES) gr = N_NODES - 1;
        int4 v = *reinterpret_cast<const int4*>(a1b + (size_t)gr * 256 + (cb >> 1));
        *reinterpret_cast<int4*>(Ab + r * 512 + (cb ^ ((r & 7) << 4))) = v;
    }
    __syncthreads();

    const int lm = l & 15, lh = l >> 4;
    f32x4 acc[4];
    #pragma unroll
    for (int rt = 0; rt < 4; ++rt) acc[rt] = (f32x4){0.f, 0.f, 0.f, 0.f};

    #pragma unroll
    for (int s = 0; s < 8; ++s) {
        int n = w * 16 + lm;
        bf16x8 bf = *reinterpret_cast<const bf16x8*>(w2t + n * 256 + s * 32 + lh * 8);
        #pragma unroll
        for (int rt = 0; rt < 4; ++rt) {
            int row = rt * 16 + lm;
            int cb = s * 64 + lh * 16;
            bf16x8 af = *reinterpret_cast<const bf16x8*>(Ab + row * 512 + (cb ^ ((row & 7) << 4)));
            acc[rt] = __builtin_amdgcn_mfma_f32_16x16x32_bf16(bf, af, acc[rt], 0, 0, 0);
        }
    }

    #pragma unroll
    for (int rt = 0; rt < 4; ++rt) {
        int row = rowbase + rt * 16 + lm;
        int col = w * 16 + lh * 4;
        float ps = 0.f, pd = 0.f;
        if (row < N_NODES) {
            ushort4 o;
            o.x = f2bf(acc[rt][0]); o.y = f2bf(acc[rt][1]);
            o.z = f2bf(acc[rt][2]); o.w = f2bf(acc[rt][3]);
            *reinterpret_cast<ushort4*>(h2 + (size_t)row * 64 + col) = o;
        }
        #pragma unroll
        for (int q = 0; q < 4; ++q) {
            ps += acc[rt][q] * att_src[col + q];
            pd += acc[rt][q] * att_dst[col + q];
        }
        ps += __shfl_xor(ps, 16); ps += __shfl_xor(ps, 32);
        pd += __shfl_xor(pd, 16); pd += __shfl_xor(pd, 32);
        if (lh == 0) { ps_s[w][rt * 16 + lm] = ps; pd_s[w][rt * 16 + lm] = pd; }
    }
    __syncthreads();
    if (tid < 64) {
        int row = rowbase + tid;
        if (row < N_NODES) {
            a_src[row] = ps_s[0][tid] + ps_s[1][tid] + ps_s[2][tid] + ps_s[3][tid];
            a_dst[row] = pd_s[0][tid] + pd_s[1][tid] + pd_s[2][tid] + pd_s[3][tid];
        }
    }
}

// ---------------- GAT layer-2 aggregation (1 head) + fused global max pool (LDS pre-reduce) ----------------
__global__ __launch_bounds__(256) void gat_agg2_pool(const unsigned short* __restrict__ h2,
                                                     const float* __restrict__ a_src,
                                                     const float* __restrict__ a_dst,
                                                     const int* __restrict__ rowstart,
                                                     const int* __restrict__ srcidx,
                                                     const float* __restrict__ b2,
                                                     const int* __restrict__ batch,
                                                     unsigned* __restrict__ g) {
    __shared__ float sm[4][64];
    const int wid = threadIdx.x >> 6;
    const int lane = threadIdx.x & 63;
    const int n = blockIdx.x * 4 + wid;          // grid covers exactly N_NODES
    const int grp = lane >> 4;
    const int cl  = lane & 15;
    int beg = rowstart[n], end = rowstart[n + 1];
    float ad = a_dst[n];

    float4 acc = make_float4(0.f, 0.f, 0.f, 0.f);
    float den_part = 0.f;
    int cb = beg;
    for (; cb + 16 <= end; cb += 16) {
        float w = 0.f; int s = 0;
        if (lane < 16) {
            s = srcidx[cb + lane];
            w = __expf(lrelu(a_src[s] + ad));
            den_part += w;
        }
        #pragma unroll
        for (int j = 0; j < 16; j += 4) {
            float wj = __shfl(w, j + grp);
            int   sj = __shfl(s, j + grp);
            ushort4 hv = *reinterpret_cast<const ushort4*>(&h2[(size_t)sj * 64 + cl * 4]);
            acc.x += wj * bf2f(hv.x); acc.y += wj * bf2f(hv.y);
            acc.z += wj * bf2f(hv.z); acc.w += wj * bf2f(hv.w);
        }
    }
    if (cb < end) {
        int cnt = end - cb;
        float w = 0.f; int s = 0;
        if (lane < cnt) {
            s = srcidx[cb + lane];
            w = __expf(lrelu(a_src[s] + ad));
            den_part += w;
        }
        for (int j = 0; j < cnt; j += 4) {
            float wj = __shfl(w, j + grp);
            int   sj = __shfl(s, j + grp);
            if (j + grp < cnt) {
                ushort4 hv = *reinterpret_cast<const ushort4*>(&h2[(size_t)sj * 64 + cl * 4]);
                acc.x += wj * bf2f(hv.x); acc.y += wj * bf2f(hv.y);
                acc.z += wj * bf2f(hv.z); acc.w += wj * bf2f(hv.w);
            }
        }
    }
    #pragma unroll
    for (int off = 16; off < 64; off <<= 1) {
        acc.x += __shfl_xor(acc.x, off);
        acc.y += __shfl_xor(acc.y, off);
        acc.z += __shfl_xor(acc.z, off);
        acc.w += __shfl_xor(acc.w, off);
    }
    #pragma unroll
    for (int off = 1; off < 64; off <<= 1) den_part += __shfl_xor(den_part, off);
    float inv = 1.f / den_part;
    float4 bv = *reinterpret_cast<const float4*>(&b2[cl * 4]);
    if (lane < 16) {
        float4 val;
        val.x = fmaxf(acc.x * inv + bv.x, 0.f);
        val.y = fmaxf(acc.y * inv + bv.y, 0.f);
        val.z = fmaxf(acc.z * inv + bv.z, 0.f);
        val.w = fmaxf(acc.w * inv + bv.w, 0.f);
        *reinterpret_cast<float4*>(&sm[wid][cl * 4]) = val;
    }
    __syncthreads();
    int b0 = batch[blockIdx.x * 4];
    int b3 = batch[blockIdx.x * 4 + 3];
    if (b0 == b3) {                               // common case: whole block same graph
        if (threadIdx.x < 64) {
            float v = fmaxf(fmaxf(sm[0][threadIdx.x], sm[1][threadIdx.x]),
                            fmaxf(sm[2][threadIdx.x], sm[3][threadIdx.x]));
            atomicMax(&g[b0 * 64 + threadIdx.x], __float_as_uint(v));  // relu => v>=0, uint order ok
        }
    } else {                                      // graph boundary inside block (rare)
        if (lane < 16) {
            int bb = batch[n];
            #pragma unroll
            for (int k = 0; k < 4; ++k)
                atomicMax(&g[bb * 64 + cl * 4 + k], __float_as_uint(sm[wid][cl * 4 + k]));
        }
    }
}

// ---------------- MLP head + log_softmax ----------------
__global__ __launch_bounds__(256) void head_kernel(const float* __restrict__ g,
                                                   const float* __restrict__ w_fc1,
                                                   const float* __restrict__ b_fc1,
                                                   const float* __restrict__ w_fc2,
                                                   const float* __restrict__ b_fc2,
                                                   float* __restrict__ out) {
    __shared__ float gs[64][65];
    __shared__ float hs[64][65];
    int t = threadIdx.x;
    #pragma unroll
    for (int it = 0; it < 16; ++it) {
        int flat = it * 256 + t;
        gs[flat >> 6][flat & 63] = g[flat];
    }
    __syncthreads();
    #pragma unroll
    for (int it = 0; it < 16; ++it) {
        int flat = it * 256 + t;
        int i = flat >> 6, j = flat & 63;
        float s = b_fc1[j];
        #pragma unroll 8
        for (int k = 0; k < 64; ++k) s += gs[i][k] * w_fc1[k * 64 + j];
        hs[i][j] = fmaxf(s, 0.f);
    }
    __syncthreads();
    if (t < 64) {
        float l0 = b_fc2[0], l1 = b_fc2[1];
        #pragma unroll 8
        for (int k = 0; k < 64; ++k) {
            float v = hs[t][k];
            l0 += v * w_fc2[k * 2];
            l1 += v * w_fc2[k * 2 + 1];
        }
        float mx = fmaxf(l0, l1);
        float lse = mx + logf(__expf(l0 - mx) + __expf(l1 - mx));
        out[t * 2]     = l0 - lse;
        out[t * 2 + 1] = l1 - lse;
    }
}

extern "C" void kernel_launch(void* const* d_in, const int* in_sizes, int n_in,
                              void* d_out, int out_size, void* d_ws, size_t ws_size,
                              hipStream_t stream) {
    const float* x        = (const float*)d_in[0];
    const int*   ei       = (const int*)d_in[1];
    const int*   batch    = (const int*)d_in[2];
    const float* W1       = (const float*)d_in[3];
    const float* att_src1 = (const float*)d_in[4];
    const float* att_dst1 = (const float*)d_in[5];
    const float* b1       = (const float*)d_in[6];
    const float* W2       = (const float*)d_in[7];
    const float* att_src2 = (const float*)d_in[8];
    const float* att_dst2 = (const float*)d_in[9];
    const float* b2       = (const float*)d_in[10];
    const float* w_fc1    = (const float*)d_in[11];
    const float* b_fc1    = (const float*)d_in[12];
    const float* w_fc2    = (const float*)d_in[13];
    const float* b_fc2    = (const float*)d_in[14];

    char* ws = (char*)d_ws;
    size_t off = 0;
    auto alloc = [&](size_t bytes) -> char* {
        char* p = ws + off;
        off += (bytes + 255) & ~(size_t)255;
        return p;
    };
    unsigned short* xb   = (unsigned short*)alloc((size_t)N_NODES * 128 * 2);
    unsigned short* w1t  = (unsigned short*)alloc((size_t)256 * 128 * 2);
    unsigned short* w2t  = (unsigned short*)alloc((size_t)64 * 256 * 2);
    unsigned short* h1   = (unsigned short*)alloc((size_t)N_NODES * 256 * 2);
    unsigned short* out1 = (unsigned short*)alloc((size_t)N_NODES * 256 * 2);
    unsigned short* h2   = (unsigned short*)alloc((size_t)N_NODES * 64 * 2);
    float*    as1        = (float*)alloc((size_t)N_NODES * 4 * 4);
    float*    ad1        = (float*)alloc((size_t)N_NODES * 4 * 4);
    float*    as2        = (float*)alloc((size_t)N_NODES * 4);
    float*    ad2        = (float*)alloc((size_t)N_NODES * 4);
    int*      counts     = (int*)alloc((size_t)N_NODES * 4);
    int*      rowstart   = (int*)alloc((size_t)(N_NODES + 4) * 4);
    int*      cursor     = (int*)alloc((size_t)(N_NODES + 4) * 4);
    int*      srcidx     = (int*)alloc((size_t)E_TOT * 4);
    unsigned* g          = (unsigned*)alloc((size_t)N_GRAPHS * HID * 4);

    // 0. zero counts (async memset is graph-capture-safe)
    hipMemsetAsync(counts, 0, (size_t)N_NODES * 4, stream);
    // 1. fused prep ∥ hist
    prep_hist_kernel<<<4076, 256, 0, stream>>>(x, W1, W2, ei, xb, w1t, w2t, counts, g);
    // 2. scan
    scan_counts<<<1, 1024, 0, stream>>>(counts, rowstart, cursor);
    // 3. fused scatter ∥ GEMM1
    scatter_gemm1<<<SCAT_B + 469, 256, 0, stream>>>(ei, cursor, srcidx,
                                                    xb, w1t, h1, att_src1, att_dst1, as1, ad1);
    // 4. layer-1 aggregation (128-thread blocks)
    gat_agg1<<<15000, 128, 0, stream>>>(h1, as1, ad1, rowstart, srcidx, b1, out1);
    // 5. layer-2 GEMM + attn dots
    mfma_gemm2<<<(N_NODES + 63) / 64, 256, 0, stream>>>(out1, w2t, h2, att_src2, att_dst2, as2, ad2);
    // 6. layer-2 aggregation + pool
    gat_agg2_pool<<<7500, 256, 0, stream>>>(h2, as2, ad2, rowstart, srcidx, b2, batch, g);
    // 7. head
    head_kernel<<<1, 256, 0, stream>>>((const float*)g, w_fc1, b_fc1, w_fc2, b_fc2, (float*)d_out);
}

// Round 11
// 190.430 us; speedup vs baseline: 1.0472x; 1.0472x over previous
//
#include <hip/hip_runtime.h>
#include <hip/hip_bf16.h>
#include <math.h>

#define N_NODES  30000
#define N_EDGESR 480000
#define E_TOT    (N_EDGESR + N_NODES)
#define N_GRAPHS 64
#define IN_DIM   128
#define HID      64
#define NEG_SLOPE 0.2f

typedef __attribute__((ext_vector_type(8))) short bf16x8;
typedef __attribute__((ext_vector_type(8))) unsigned short u16x8;
typedef __attribute__((ext_vector_type(4))) float f32x4;

__device__ __forceinline__ float lrelu(float v) { return v > 0.f ? v : NEG_SLOPE * v; }
__device__ __forceinline__ float bf2f(unsigned short u) { return __uint_as_float((unsigned)u << 16); }
__device__ __forceinline__ unsigned short f2bf(float f) {
    return __bfloat16_as_ushort(__float2bfloat16(f));
}

// ---------------- prep: zero counts+pool, x->bf16, W1/W2 -> transposed bf16 ----------------
__global__ __launch_bounds__(256) void prep_kernel(const float* __restrict__ x,
                                                   const float* __restrict__ W1,
                                                   const float* __restrict__ W2,
                                                   unsigned short* __restrict__ xb,
                                                   unsigned short* __restrict__ w1t,
                                                   unsigned short* __restrict__ w2t,
                                                   int* __restrict__ counts,
                                                   unsigned* __restrict__ g) {
    int t = blockIdx.x * 256 + threadIdx.x;
    if (t < 480000) {                               // x -> bf16, 8 elems/thread
        int i = t * 8;
        float4 v0 = *reinterpret_cast<const float4*>(x + i);
        float4 v1 = *reinterpret_cast<const float4*>(x + i + 4);
        u16x8 o;
        o[0] = f2bf(v0.x); o[1] = f2bf(v0.y); o[2] = f2bf(v0.z); o[3] = f2bf(v0.w);
        o[4] = f2bf(v1.x); o[5] = f2bf(v1.y); o[6] = f2bf(v1.z); o[7] = f2bf(v1.w);
        *reinterpret_cast<u16x8*>(xb + i) = o;
    } else if (t < 510000) {
        counts[t - 480000] = 0;
    } else if (t < 514096) {
        g[t - 510000] = 0u;
    } else if (t < 546864) {                        // W1 [128][256] -> w1t [256][128]
        int id = t - 514096;
        int k = id >> 8, n = id & 255;
        w1t[n * 128 + k] = f2bf(W1[id]);
    } else if (t < 563248) {                        // W2 [256][64] -> w2t [64][256]
        int id = t - 546864;
        int k = id >> 6, n = id & 63;
        w2t[n * 256 + k] = f2bf(W2[id]);
    }
}

// ---------------- CSR build ----------------
__global__ void edge_hist(const int* __restrict__ ei, int* __restrict__ counts) {
    int e = blockIdx.x * blockDim.x + threadIdx.x;
    if (e >= E_TOT) return;
    int d = (e < N_EDGESR) ? ei[N_EDGESR + e] : (e - N_EDGESR);
    atomicAdd(&counts[d], 1);
}

__global__ __launch_bounds__(1024) void scan_counts(const int* __restrict__ counts,
                                                    int* __restrict__ rowstart,
                                                    int* __restrict__ cursor) {
    __shared__ int bufA[1024];
    __shared__ int bufB[1024];
    const int t = threadIdx.x;
    const int CH = 30;
    int local[CH];
    int base = t * CH;
    int s = 0;
    #pragma unroll
    for (int i = 0; i < CH; ++i) {
        int idx = base + i;
        int c = (idx < N_NODES) ? counts[idx] : 0;
        local[i] = c; s += c;
    }
    bufA[t] = s;
    __syncthreads();
    int* a = bufA; int* b = bufB;
    for (int off = 1; off < 1024; off <<= 1) {
        int v = a[t] + ((t >= off) ? a[t - off] : 0);
        b[t] = v;
        __syncthreads();
        int* tmp = a; a = b; b = tmp;
    }
    int run = (t == 0) ? 0 : a[t - 1];
    #pragma unroll
    for (int i = 0; i < CH; ++i) {
        int idx = base + i;
        if (idx < N_NODES) { rowstart[idx] = run; cursor[idx] = run; run += local[i]; }
    }
    if (t == 0) rowstart[N_NODES] = E_TOT;
}

__global__ void edge_scatter(const int* __restrict__ ei, int* __restrict__ cursor,
                             int* __restrict__ srcidx) {
    int e = blockIdx.x * blockDim.x + threadIdx.x;
    if (e >= E_TOT) return;
    int s, d;
    if (e < N_EDGESR) { s = ei[e]; d = ei[N_EDGESR + e]; }
    else              { s = d = e - N_EDGESR; }
    int pos = atomicAdd(&cursor[d], 1);
    srcidx[pos] = s;
}

// ---- MFMA GEMM1: h1[30000,256] = xb[30000,128] @ W1 (w1t is [256][128] bf16) ----
// block = 64 rows; wave w = head w (cols w*64..+63). Fused attn-dot epilogue.
__global__ __launch_bounds__(256) void mfma_gemm1(const unsigned short* __restrict__ xb,
                                                  const unsigned short* __restrict__ w1t,
                                                  unsigned short* __restrict__ h1,
                                                  const float* __restrict__ att_src,
                                                  const float* __restrict__ att_dst,
                                                  float* __restrict__ a_src,
                                                  float* __restrict__ a_dst) {
    __shared__ __align__(16) unsigned short As[64 * 128];  // 16 KB, row stride 256 B, XOR-swizzled
    const int tid = threadIdx.x;
    const int w = tid >> 6;
    const int l = tid & 63;
    const int rowbase = blockIdx.x * 64;
    char* Ab = (char*)As;

    #pragma unroll
    for (int i = 0; i < 4; ++i) {
        int flat = i * 256 + tid;            // 16B-chunk id 0..1023
        int r = flat >> 4;                   // row 0..63
        int cb = (flat & 15) * 16;           // byte col
        int gr = rowbase + r; if (gr >= N_NODES) gr = N_NODES - 1;
        int4 v = *reinterpret_cast<const int4*>(xb + (size_t)gr * 128 + (cb >> 1));
        *reinterpret_cast<int4*>(Ab + r * 256 + (cb ^ ((r & 7) << 4))) = v;
    }
    __syncthreads();

    const int lm = l & 15, lh = l >> 4;
    f32x4 acc[4][4];
    #pragma unroll
    for (int rt = 0; rt < 4; ++rt)
        #pragma unroll
        for (int ct = 0; ct < 4; ++ct)
            acc[rt][ct] = (f32x4){0.f, 0.f, 0.f, 0.f};

    #pragma unroll
    for (int s = 0; s < 4; ++s) {
        bf16x8 bfr[4], afr[4];
        #pragma unroll
        for (int ct = 0; ct < 4; ++ct) {
            int n = w * 64 + ct * 16 + lm;
            bfr[ct] = *reinterpret_cast<const bf16x8*>(w1t + n * 128 + s * 32 + lh * 8);
        }
        #pragma unroll
        for (int rt = 0; rt < 4; ++rt) {
            int row = rt * 16 + lm;
            int cb = s * 64 + lh * 16;
            afr[rt] = *reinterpret_cast<const bf16x8*>(Ab + row * 256 + (cb ^ ((row & 7) << 4)));
        }
        #pragma unroll
        for (int rt = 0; rt < 4; ++rt)
            #pragma unroll
            for (int ct = 0; ct < 4; ++ct)
                acc[rt][ct] = __builtin_amdgcn_mfma_f32_16x16x32_bf16(bfr[ct], afr[rt], acc[rt][ct], 0, 0, 0);
    }

    // epilogue: bf16 C write (8B packed) + fused attention dots for head w
    #pragma unroll
    for (int rt = 0; rt < 4; ++rt) {
        int row = rowbase + rt * 16 + lm;
        float ps = 0.f, pd = 0.f;
        #pragma unroll
        for (int ct = 0; ct < 4; ++ct) {
            int col = w * 64 + ct * 16 + lh * 4;
            if (row < N_NODES) {
                ushort4 o;
                o.x = f2bf(acc[rt][ct][0]); o.y = f2bf(acc[rt][ct][1]);
                o.z = f2bf(acc[rt][ct][2]); o.w = f2bf(acc[rt][ct][3]);
                *reinterpret_cast<ushort4*>(h1 + (size_t)row * 256 + col) = o;
            }
            #pragma unroll
            for (int q = 0; q < 4; ++q) {
                ps += acc[rt][ct][q] * att_src[col + q];
                pd += acc[rt][ct][q] * att_dst[col + q];
            }
        }
        ps += __shfl_xor(ps, 16); ps += __shfl_xor(ps, 32);
        pd += __shfl_xor(pd, 16); pd += __shfl_xor(pd, 32);
        if (lh == 0 && row < N_NODES) {
            a_src[row * 4 + w] = ps;
            a_dst[row * 4 + w] = pd;
        }
    }
}

// ---------------- GAT layer-1 aggregation — 1 wave per block (no inter-wave imbalance) ----------------
__global__ __launch_bounds__(64) void gat_agg1(const unsigned short* __restrict__ h1,
                                               const float* __restrict__ a_src,
                                               const float* __restrict__ a_dst,
                                               const int* __restrict__ rowstart,
                                               const int* __restrict__ srcidx,
                                               const float* __restrict__ b1,
                                               unsigned short* __restrict__ out1) {
    int n = blockIdx.x;
    int lane = threadIdx.x;
    int beg = rowstart[n], end = rowstart[n + 1];
    const int h    = lane & 3;
    const int slot = lane >> 2;
    const int half = lane >> 5;
    const int cl   = lane & 31;
    const int myhead = cl >> 3;
    float ad_h = a_dst[n * 4 + h];

    float acc[8] = {};
    float den_part = 0.f;
    int cb = beg;
    for (; cb + 16 <= end; cb += 16) {
        int s = srcidx[cb + slot];
        float w = __expf(lrelu(a_src[s * 4 + h] + ad_h));   // bounded logits: no max needed
        den_part += w;
        #pragma unroll
        for (int j = 0; j < 16; j += 2) {
            int e = j + half;
            float wj = __shfl(w, e * 4 + myhead);
            int   sj = __shfl(s, e * 4);
            u16x8 hv = *reinterpret_cast<const u16x8*>(h1 + (size_t)sj * 256 + cl * 8);
            #pragma unroll
            for (int q = 0; q < 8; ++q) acc[q] += wj * bf2f((unsigned short)hv[q]);
        }
    }
    if (cb < end) {
        int cnt = end - cb;                      // 1..15
        float w = 0.f; int s = 0;
        if (slot < cnt) {
            s = srcidx[cb + slot];
            w = __expf(lrelu(a_src[s * 4 + h] + ad_h));
            den_part += w;
        }
        for (int j = 0; j < cnt; j += 2) {
            int e = j + half;
            float wj = __shfl(w, e * 4 + myhead);
            int   sj = __shfl(s, e * 4);
            if (e < cnt) {
                u16x8 hv = *reinterpret_cast<const u16x8*>(h1 + (size_t)sj * 256 + cl * 8);
                #pragma unroll
                for (int q = 0; q < 8; ++q) acc[q] += wj * bf2f((unsigned short)hv[q]);
            }
        }
    }
    #pragma unroll
    for (int q = 0; q < 8; ++q) acc[q] += __shfl_xor(acc[q], 32);
    #pragma unroll
    for (int off = 4; off < 64; off <<= 1) den_part += __shfl_xor(den_part, off);
    float inv = 1.f / __shfl(den_part, myhead);
    if (half == 0) {
        float4 bv0 = *reinterpret_cast<const float4*>(b1 + cl * 8);
        float4 bv1 = *reinterpret_cast<const float4*>(b1 + cl * 8 + 4);
        u16x8 o;
        o[0] = f2bf(fmaxf(acc[0] * inv + bv0.x, 0.f));
        o[1] = f2bf(fmaxf(acc[1] * inv + bv0.y, 0.f));
        o[2] = f2bf(fmaxf(acc[2] * inv + bv0.z, 0.f));
        o[3] = f2bf(fmaxf(acc[3] * inv + bv0.w, 0.f));
        o[4] = f2bf(fmaxf(acc[4] * inv + bv1.x, 0.f));
        o[5] = f2bf(fmaxf(acc[5] * inv + bv1.y, 0.f));
        o[6] = f2bf(fmaxf(acc[6] * inv + bv1.z, 0.f));
        o[7] = f2bf(fmaxf(acc[7] * inv + bv1.w, 0.f));
        // non-temporal: out1 is only read by gemm2 later; keep L2 for the h1 gather table
        __builtin_nontemporal_store(o, reinterpret_cast<u16x8*>(out1 + (size_t)n * 256 + cl * 8));
    }
}

// ---- MFMA GEMM2: h2[30000,64] = out1[30000,256] @ W2 (w2t [64][256] bf16) + fused attn dots ----
__global__ __launch_bounds__(256) void mfma_gemm2(const unsigned short* __restrict__ a1b,
                                                  const unsigned short* __restrict__ w2t,
                                                  unsigned short* __restrict__ h2,
                                                  const float* __restrict__ att_src,
                                                  const float* __restrict__ att_dst,
                                                  float* __restrict__ a_src,
                                                  float* __restrict__ a_dst) {
    __shared__ __align__(16) unsigned short As[64 * 256];  // 32 KB, swizzled
    __shared__ float ps_s[4][64], pd_s[4][64];
    const int tid = threadIdx.x;
    const int w = tid >> 6, l = tid & 63;
    const int rowbase = blockIdx.x * 64;
    char* Ab = (char*)As;

    #pragma unroll
    for (int i = 0; i < 8; ++i) {
        int flat = i * 256 + tid;
        int r = flat >> 5;
        int cb = (flat & 31) * 16;
        int gr = rowbase + r; if (gr >= N_NODES) gr = N_NODES - 1;
        int4 v = *reinterpret_cast<const int4*>(a1b + (size_t)gr * 256 + (cb >> 1));
        *reinterpret_cast<int4*>(Ab + r * 512 + (cb ^ ((r & 7) << 4))) = v;
    }
    __syncthreads();

    const int lm = l & 15, lh = l >> 4;
    f32x4 acc[4];
    #pragma unroll
    for (int rt = 0; rt < 4; ++rt) acc[rt] = (f32x4){0.f, 0.f, 0.f, 0.f};

    #pragma unroll
    for (int s = 0; s < 8; ++s) {
        int n = w * 16 + lm;
        bf16x8 bf = *reinterpret_cast<const bf16x8*>(w2t + n * 256 + s * 32 + lh * 8);
        #pragma unroll
        for (int rt = 0; rt < 4; ++rt) {
            int row = rt * 16 + lm;
            int cb = s * 64 + lh * 16;
            bf16x8 af = *reinterpret_cast<const bf16x8*>(Ab + row * 512 + (cb ^ ((row & 7) << 4)));
            acc[rt] = __builtin_amdgcn_mfma_f32_16x16x32_bf16(bf, af, acc[rt], 0, 0, 0);
        }
    }

    #pragma unroll
    for (int rt = 0; rt < 4; ++rt) {
        int row = rowbase + rt * 16 + lm;
        int col = w * 16 + lh * 4;
        float ps = 0.f, pd = 0.f;
        if (row < N_NODES) {
            ushort4 o;
            o.x = f2bf(acc[rt][0]); o.y = f2bf(acc[rt][1]);
            o.z = f2bf(acc[rt][2]); o.w = f2bf(acc[rt][3]);
            *reinterpret_cast<ushort4*>(h2 + (size_t)row * 64 + col) = o;
        }
        #pragma unroll
        for (int q = 0; q < 4; ++q) {
            ps += acc[rt][q] * att_src[col + q];
            pd += acc[rt][q] * att_dst[col + q];
        }
        ps += __shfl_xor(ps, 16); ps += __shfl_xor(ps, 32);
        pd += __shfl_xor(pd, 16); pd += __shfl_xor(pd, 32);
        if (lh == 0) { ps_s[w][rt * 16 + lm] = ps; pd_s[w][rt * 16 + lm] = pd; }
    }
    __syncthreads();
    if (tid < 64) {
        int row = rowbase + tid;
        if (row < N_NODES) {
            a_src[row] = ps_s[0][tid] + ps_s[1][tid] + ps_s[2][tid] + ps_s[3][tid];
            a_dst[row] = pd_s[0][tid] + pd_s[1][tid] + pd_s[2][tid] + pd_s[3][tid];
        }
    }
}

// ---------------- GAT layer-2 aggregation (1 head) + fused global max pool (LDS pre-reduce) ----------------
__global__ __launch_bounds__(256) void gat_agg2_pool(const unsigned short* __restrict__ h2,
                                                     const float* __restrict__ a_src,
                                                     const float* __restrict__ a_dst,
                                                     const int* __restrict__ rowstart,
                                                     const int* __restrict__ srcidx,
                                                     const float* __restrict__ b2,
                                                     const int* __restrict__ batch,
                                                     unsigned* __restrict__ g) {
    __shared__ float sm[4][64];
    const int wid = threadIdx.x >> 6;
    const int lane = threadIdx.x & 63;
    const int n = blockIdx.x * 4 + wid;          // grid covers exactly N_NODES
    const int grp = lane >> 4;
    const int cl  = lane & 15;
    int beg = rowstart[n], end = rowstart[n + 1];
    float ad = a_dst[n];

    float4 acc = make_float4(0.f, 0.f, 0.f, 0.f);
    float den_part = 0.f;
    int cb = beg;
    for (; cb + 16 <= end; cb += 16) {
        float w = 0.f; int s = 0;
        if (lane < 16) {
            s = srcidx[cb + lane];
            w = __expf(lrelu(a_src[s] + ad));
            den_part += w;
        }
        #pragma unroll
        for (int j = 0; j < 16; j += 4) {
            float wj = __shfl(w, j + grp);
            int   sj = __shfl(s, j + grp);
            ushort4 hv = *reinterpret_cast<const ushort4*>(&h2[(size_t)sj * 64 + cl * 4]);
            acc.x += wj * bf2f(hv.x); acc.y += wj * bf2f(hv.y);
            acc.z += wj * bf2f(hv.z); acc.w += wj * bf2f(hv.w);
        }
    }
    if (cb < end) {
        int cnt = end - cb;
        float w = 0.f; int s = 0;
        if (lane < cnt) {
            s = srcidx[cb + lane];
            w = __expf(lrelu(a_src[s] + ad));
            den_part += w;
        }
        for (int j = 0; j < cnt; j += 4) {
            float wj = __shfl(w, j + grp);
            int   sj = __shfl(s, j + grp);
            if (j + grp < cnt) {
                ushort4 hv = *reinterpret_cast<const ushort4*>(&h2[(size_t)sj * 64 + cl * 4]);
                acc.x += wj * bf2f(hv.x); acc.y += wj * bf2f(hv.y);
                acc.z += wj * bf2f(hv.z); acc.w += wj * bf2f(hv.w);
            }
        }
    }
    #pragma unroll
    for (int off = 16; off < 64; off <<= 1) {
        acc.x += __shfl_xor(acc.x, off);
        acc.y += __shfl_xor(acc.y, off);
        acc.z += __shfl_xor(acc.z, off);
        acc.w += __shfl_xor(acc.w, off);
    }
    #pragma unroll
    for (int off = 1; off < 64; off <<= 1) den_part += __shfl_xor(den_part, off);
    float inv = 1.f / den_part;
    float4 bv = *reinterpret_cast<const float4*>(&b2[cl * 4]);
    if (lane < 16) {
        float4 val;
        val.x = fmaxf(acc.x * inv + bv.x, 0.f);
        val.y = fmaxf(acc.y * inv + bv.y, 0.f);
        val.z = fmaxf(acc.z * inv + bv.z, 0.f);
        val.w = fmaxf(acc.w * inv + bv.w, 0.f);
        *reinterpret_cast<float4*>(&sm[wid][cl * 4]) = val;
    }
    __syncthreads();
    int b0 = batch[blockIdx.x * 4];
    int b3 = batch[blockIdx.x * 4 + 3];
    if (b0 == b3) {                               // common case: whole block same graph
        if (threadIdx.x < 64) {
            float v = fmaxf(fmaxf(sm[0][threadIdx.x], sm[1][threadIdx.x]),
                            fmaxf(sm[2][threadIdx.x], sm[3][threadIdx.x]));
            atomicMax(&g[b0 * 64 + threadIdx.x], __float_as_uint(v));  // relu => v>=0, uint order ok
        }
    } else {                                      // graph boundary inside block (rare)
        if (lane < 16) {
            int bb = batch[n];
            #pragma unroll
            for (int k = 0; k < 4; ++k)
                atomicMax(&g[bb * 64 + cl * 4 + k], __float_as_uint(sm[wid][cl * 4 + k]));
        }
    }
}

// ---------------- MLP head + log_softmax ----------------
__global__ __launch_bounds__(256) void head_kernel(const float* __restrict__ g,
                                                   const float* __restrict__ w_fc1,
                                                   const float* __restrict__ b_fc1,
                                                   const float* __restrict__ w_fc2,
                                                   const float* __restrict__ b_fc2,
                                                   float* __restrict__ out) {
    __shared__ float gs[64][65];
    __shared__ float hs[64][65];
    int t = threadIdx.x;
    #pragma unroll
    for (int it = 0; it < 16; ++it) {
        int flat = it * 256 + t;
        gs[flat >> 6][flat & 63] = g[flat];
    }
    __syncthreads();
    #pragma unroll
    for (int it = 0; it < 16; ++it) {
        int flat = it * 256 + t;
        int i = flat >> 6, j = flat & 63;
        float s = b_fc1[j];
        #pragma unroll 8
        for (int k = 0; k < 64; ++k) s += gs[i][k] * w_fc1[k * 64 + j];
        hs[i][j] = fmaxf(s, 0.f);
    }
    __syncthreads();
    if (t < 64) {
        float l0 = b_fc2[0], l1 = b_fc2[1];
        #pragma unroll 8
        for (int k = 0; k < 64; ++k) {
            float v = hs[t][k];
            l0 += v * w_fc2[k * 2];
            l1 += v * w_fc2[k * 2 + 1];
        }
        float mx = fmaxf(l0, l1);
        float lse = mx + logf(__expf(l0 - mx) + __expf(l1 - mx));
        out[t * 2]     = l0 - lse;
        out[t * 2 + 1] = l1 - lse;
    }
}

extern "C" void kernel_launch(void* const* d_in, const int* in_sizes, int n_in,
                              void* d_out, int out_size, void* d_ws, size_t ws_size,
                              hipStream_t stream) {
    const float* x        = (const float*)d_in[0];
    const int*   ei       = (const int*)d_in[1];
    const int*   batch    = (const int*)d_in[2];
    const float* W1       = (const float*)d_in[3];
    const float* att_src1 = (const float*)d_in[4];
    const float* att_dst1 = (const float*)d_in[5];
    const float* b1       = (const float*)d_in[6];
    const float* W2       = (const float*)d_in[7];
    const float* att_src2 = (const float*)d_in[8];
    const float* att_dst2 = (const float*)d_in[9];
    const float* b2       = (const float*)d_in[10];
    const float* w_fc1    = (const float*)d_in[11];
    const float* b_fc1    = (const float*)d_in[12];
    const float* w_fc2    = (const float*)d_in[13];
    const float* b_fc2    = (const float*)d_in[14];

    char* ws = (char*)d_ws;
    size_t off = 0;
    auto alloc = [&](size_t bytes) -> char* {
        char* p = ws + off;
        off += (bytes + 255) & ~(size_t)255;
        return p;
    };
    unsigned short* xb   = (unsigned short*)alloc((size_t)N_NODES * 128 * 2);
    unsigned short* w1t  = (unsigned short*)alloc((size_t)256 * 128 * 2);
    unsigned short* w2t  = (unsigned short*)alloc((size_t)64 * 256 * 2);
    unsigned short* h1   = (unsigned short*)alloc((size_t)N_NODES * 256 * 2);
    unsigned short* out1 = (unsigned short*)alloc((size_t)N_NODES * 256 * 2);
    unsigned short* h2   = (unsigned short*)alloc((size_t)N_NODES * 64 * 2);
    float*    as1        = (float*)alloc((size_t)N_NODES * 4 * 4);
    float*    ad1        = (float*)alloc((size_t)N_NODES * 4 * 4);
    float*    as2        = (float*)alloc((size_t)N_NODES * 4);
    float*    ad2        = (float*)alloc((size_t)N_NODES * 4);
    int*      counts     = (int*)alloc((size_t)N_NODES * 4);
    int*      rowstart   = (int*)alloc((size_t)(N_NODES + 4) * 4);
    int*      cursor     = (int*)alloc((size_t)(N_NODES + 4) * 4);
    int*      srcidx     = (int*)alloc((size_t)E_TOT * 4);
    unsigned* g          = (unsigned*)alloc((size_t)N_GRAPHS * HID * 4);

    // 1. prep: zero + conversions
    prep_kernel<<<2201, 256, 0, stream>>>(x, W1, W2, xb, w1t, w2t, counts, g);
    // 2-4. CSR by dst (shared by both layers)
    edge_hist<<<(E_TOT + 255) / 256, 256, 0, stream>>>(ei, counts);
    scan_counts<<<1, 1024, 0, stream>>>(counts, rowstart, cursor);
    edge_scatter<<<(E_TOT + 255) / 256, 256, 0, stream>>>(ei, cursor, srcidx);
    // 5-6. layer 1
    mfma_gemm1<<<(N_NODES + 63) / 64, 256, 0, stream>>>(xb, w1t, h1, att_src1, att_dst1, as1, ad1);
    gat_agg1<<<N_NODES, 64, 0, stream>>>(h1, as1, ad1, rowstart, srcidx, b1, out1);
    // 7-8. layer 2
    mfma_gemm2<<<(N_NODES + 63) / 64, 256, 0, stream>>>(out1, w2t, h2, att_src2, att_dst2, as2, ad2);
    gat_agg2_pool<<<7500, 256, 0, stream>>>(h2, as2, ad2, rowstart, srcidx, b2, batch, g);
    // 9. head
    head_kernel<<<1, 256, 0, stream>>>((const float*)g, w_fc1, b_fc1, w_fc2, b_fc2, (float*)d_out);
}